// Round 9
// baseline (89.087 us; speedup 1.0000x reference)
//
#include <hip/hip_runtime.h>
#include <hip/hip_bf16.h>

// RuleGraphConvLayer R9: software-pipelined tiles (stage t+1 in regs under
// MFMA of t), single-buffered LDS, col-split MFMA with hoisted B frags.
// K = 192 slots: [0..80] self, [81..95] pad(B=0), [96..176] comb, [177..191] pad.
constexpr int kNodes = 262144;
constexpr int NC  = 103;   // feature columns
constexpr int F   = 81;    // used features
constexpr int OC  = 128;   // output channels
constexpr int NKS = 6;     // 6*32 = 192 K slots
constexpr int NPB = 64;    // nodes per tile
constexpr int TPB = 4;     // tiles per block (block = 256 nodes)
constexpr int THREADS = 256;
constexpr int NEI_STRIDE = 100;       // 96 used + 4 pad
constexpr int GW = 96;                // dwords gathered per nei row
constexpr int SELF_F4 = NPB * NC / 4; // 1648 float4 per tile

typedef __attribute__((ext_vector_type(8))) short bf16x8;
typedef __attribute__((ext_vector_type(4))) float f32x4;

__device__ inline ushort f2bf(float f) {
  uint u = __float_as_uint(f);
  return (ushort)((u + 0x7fffu + ((u >> 16) & 1u)) >> 16);  // RNE
}
__device__ inline short bfc(float x) {
  return (short)__bfloat16_as_ushort(__float2bfloat16(x));
}

// B table in fragment order: wf[ks][ct][lane] = 8 bf16.
// B[k][c]: k = ks*32 + (lane>>4)*8 + i, c = ct*16 + (lane&15).
// Rows: k<81 -> w_s[k]; 96<=k<177 -> w_n[k-96]; else 0.
__global__ __launch_bounds__(256)
void prep_w(const float* __restrict__ w_s, const float* __restrict__ w_n,
            ushort* __restrict__ wf) {
  int t = blockIdx.x * 256 + threadIdx.x;
  if (t >= NKS * 8 * 64) return;
  int l  = t & 63;
  int ct = (t >> 6) & 7;
  int ks = t >> 9;
  int c  = ct * 16 + (l & 15);
  int kb = ks * 32 + ((l >> 4) << 3);
  union { ushort u[8]; int4 v; } o;
  #pragma unroll
  for (int i = 0; i < 8; ++i) {
    int k = kb + i;
    float f = 0.f;
    if (k < F)                      f = w_s[k * OC + c];
    else if (k >= 96 && k < 96 + F) f = w_n[(k - 96) * OC + c];
    o.u[i] = f2bf(f);
  }
  ((int4*)wf)[t] = o.v;
}

__global__ __launch_bounds__(THREADS)
void rgc_v9(const float* __restrict__ feat, const ushort* __restrict__ wf,
            float* __restrict__ out) {
  __shared__ __align__(16) float lds_self[NPB * NC];          // 26368 B
  __shared__ __align__(16) float lds_nei[NPB * NEI_STRIDE];   // 25600 B
  __shared__ int   s_sel[THREADS];                            // 256 nodes
  __shared__ float s_cs[THREADS];                             // alive folded in

  const int tid = threadIdx.x;
  const int w   = tid >> 6;
  const int l   = tid & 63;
  const long bbase = (long)blockIdx.x * (NPB * TPB);

  // ---- Hoisted B fragments: wave w owns ct = {w, w+4} (12 x 16B, once).
  const bf16x8* wfv = (const bf16x8*)wf;
  bf16x8 bA[NKS], bB[NKS];
  #pragma unroll
  for (int ks = 0; ks < NKS; ++ks) {
    bA[ks] = wfv[(ks * 8 + w)     * 64 + l];
    bB[ks] = wfv[(ks * 8 + w + 4) * 64 + l];
  }

  // ---- Meta prologue: sel + cs for ALL 256 nodes, one node per thread,
  // one latency exposure (8 independent scalar loads per thread).
  {
    const float* row = feat + (bbase + tid) * NC;
    float f0 = row[F], f1 = row[F + 1];
    int i0 = (int)f0, i1 = (int)f1;
    int sel = (i1 != 0) ? i1 : i0;          // alive <=> sel != 0
    const float* nr = feat + (long)sel * NC;
    float dx = row[0] - nr[0];
    float dy = row[1] - nr[1];
    float dz = row[2] - nr[2];
    float d2 = dx * dx + dy * dy + dz * dz;
    float alive = (sel != 0) ? 1.f : 0.f;
    s_sel[tid] = sel;
    s_cs[tid]  = alive * ((d2 > 0.f) ? (1.f / d2) : 10000.f);
  }
  __syncthreads();

  // ---- Staging registers for one tile: 7 float4 self + 24 nei dwords.
  f32x4 st[7];
  f32x4 ng[6];

#define STAGE(T)                                                            \
  {                                                                         \
    const f32x4* src = (const f32x4*)(feat + (bbase + (long)(T) * NPB) * NC); \
    _Pragma("unroll")                                                       \
    for (int j = 0; j < 6; ++j) st[j] = src[tid + j * THREADS];             \
    if (tid < SELF_F4 - 6 * THREADS) st[6] = src[tid + 6 * THREADS];        \
    _Pragma("unroll")                                                       \
    for (int j = 0; j < 24; ++j) {                                          \
      int v = tid + j * THREADS;                                            \
      int r = v / GW;                                                       \
      int c = v - r * GW;                                                   \
      ng[j >> 2][j & 3] = feat[(long)s_sel[(T) * NPB + r] * NC + c];        \
    }                                                                       \
    asm volatile("" :: "v"(st[0]), "v"(st[1]), "v"(st[2]), "v"(st[3]),      \
                       "v"(st[4]), "v"(st[5]), "v"(st[6]));                 \
    asm volatile("" :: "v"(ng[0]), "v"(ng[1]), "v"(ng[2]), "v"(ng[3]),      \
                       "v"(ng[4]), "v"(ng[5]));                             \
  }

  STAGE(0);

  const int q    = l >> 4;
  const int lrow = l & 15;
  const int off0 = q * 8;
  const int col  = l & 15;

  for (int t = 0; t < TPB; ++t) {
    // ---- Dump staged regs -> LDS (raw f32).
    {
      f32x4* dst = (f32x4*)lds_self;
      #pragma unroll
      for (int j = 0; j < 6; ++j) dst[tid + j * THREADS] = st[j];
      if (tid < SELF_F4 - 6 * THREADS) dst[tid + 6 * THREADS] = st[6];
      #pragma unroll
      for (int j = 0; j < 24; ++j) {
        int v = tid + j * THREADS;
        int r = v / GW;
        int c = v - r * GW;
        lds_nei[r * NEI_STRIDE + c] = ng[j >> 2][j & 3];
      }
    }
    __syncthreads();   // LDS(t) ready

    // ---- Issue next tile's loads NOW; they fly under MFMA(t).
    if (t + 1 < TPB) STAGE(t + 1);

    // ---- MFMA on tile t: 4 node-tiles x 2 column tiles (col-split).
    #pragma unroll
    for (int nt = 0; nt < 4; ++nt) {
      const int n = nt * 16 + lrow;
      const float* sp = lds_self + n * NC;
      const float* np = lds_nei + n * NEI_STRIDE;
      const float alive = (s_sel[t * NPB + n] != 0) ? 1.f : 0.f;
      const float cs    = s_cs[t * NPB + n];

      bf16x8 afS[3], afC[3];
      #pragma unroll
      for (int c = 0; c < 3; ++c) {
        #pragma unroll
        for (int i = 0; i < 8; ++i) {
          float sv = sp[c * 32 + off0 + i];
          float nv = np[c * 32 + off0 + i];
          afS[c][i] = bfc(sv * alive);
          float se = sv;
          if (c == 0 && i < 3 && q == 0) se = 0.f;  // comb kk<3: nei coords only
          afC[c][i] = bfc((nv + se) * cs);
        }
      }

      f32x4 a0 = (f32x4)(0.f), a1 = (f32x4)(0.f);
      #pragma unroll
      for (int ks = 0; ks < NKS; ++ks) {
        bf16x8 af = (ks < 3) ? afS[ks] : afC[ks - 3];
        a0 = __builtin_amdgcn_mfma_f32_16x16x32_bf16(af, bA[ks], a0, 0, 0, 0);
        a1 = __builtin_amdgcn_mfma_f32_16x16x32_bf16(af, bB[ks], a1, 0, 0, 0);
      }

      // C/D: col = lane&15, row = (lane>>4)*4 + reg  [m89/m91]
      const long orow = bbase + t * NPB + nt * 16 + q * 4;
      #pragma unroll
      for (int r = 0; r < 4; ++r) {
        out[(orow + r) * OC + w * 16       + col] = a0[r];
        out[(orow + r) * OC + (w + 4) * 16 + col] = a1[r];
      }
    }
    __syncthreads();   // all waves done reading LDS(t)
  }
#undef STAGE
}

extern "C" void kernel_launch(void* const* d_in, const int* in_sizes, int n_in,
                              void* d_out, int out_size, void* d_ws, size_t ws_size,
                              hipStream_t stream) {
  const float* feat = (const float*)d_in[0];
  const float* w_s  = (const float*)d_in[1];
  const float* w_n  = (const float*)d_in[2];
  float* outp = (float*)d_out;
  ushort* wf = (ushort*)d_ws;  // 6*8*64*8 bf16 = 49152 bytes

  prep_w<<<dim3((NKS * 8 * 64 + 255) / 256), 256, 0, stream>>>(w_s, w_n, wf);
  rgc_v9<<<dim3(kNodes / (NPB * TPB)), THREADS, 0, stream>>>(feat, wf, outp);
}